// Round 7
// baseline (2794.359 us; speedup 1.0000x reference)
//
#include <hip/hip_runtime.h>

#define NVARS    12000
#define NNODES   8400
#define NLEAF    3600
#define NROUNDS  12
#define RPB      48              // rows per block (best weight amortization)
#define NB       250             // blocks (250*48 = 12000; node boundary = 175*48)
#define NODE_BLKS 175
#define CAP      64              // CSR fan-in cap (mean ~10, P(>64) ~ 0)
#define TPB      768             // 12 waves: wave w -> (mt = w>>2, colgroup = w&3)
#define CTPB     256             // helper-kernel block size

typedef _Float16 f16;
typedef _Float16 half8 __attribute__((ext_vector_type(8)));
typedef _Float16 half4v __attribute__((ext_vector_type(4)));
typedef float f32x4 __attribute__((ext_vector_type(4)));
typedef unsigned long long ull;

#define MROW 136                 // LDS plane row stride in halves (272B, 16B-aligned)
#define PLANE (RPB * MROW)       // 6528 halves per plane

struct Params {
    float *t1a, *t1b;
    int *bar;
    const int *vt, *ncnt, *nidx, *vcnt, *vidx;
    const float *true_w, *true_b, *false_w, *false_b;
    const f16 *wm_hi, *wm_lo;          // 8 MLP mats [n=128][k=128] hi/lo
    const f16 *vu_hi, *vu_lo;          // [512][256] (k<128: wih, k>=128: whh)
    const f16 *nu_hi, *nu_lo;
    const float *cm_b1, *cm_b2, *cm_b3, *pm_b1, *pm_b2, *pm_b3;
    const float *vv_b1, *vv_b2, *vv_w3, *vv_b3;
    const float *vu_bih, *vu_bhh, *nu_bih, *nu_bhh;
    float *out;
};

__device__ __forceinline__ float sigm(float x) { return 1.f / (1.f + expf(-x)); }

// ---- software grid barrier, FENCELESS (proven r3: -20%). Sharded arrivals,
// LOAD-only agent-scope spin. vmcnt(0) drain before s_barrier makes all
// agent-scope t1 stores globally visible -> no threadfence, L2 stays
// weight-hot across rounds.
__device__ __forceinline__ void gsync(int* bar, int target) {
    __builtin_amdgcn_s_waitcnt(0);
    __syncthreads();
    if (threadIdx.x == 0) {
        __hip_atomic_fetch_add(&bar[(blockIdx.x & 7) << 4], 1,
                               __ATOMIC_RELAXED, __HIP_MEMORY_SCOPE_AGENT);
        for (;;) {
            int s = 0;
#pragma unroll
            for (int k = 0; k < 8; ++k)
                s += __hip_atomic_load(&bar[k << 4], __ATOMIC_RELAXED,
                                       __HIP_MEMORY_SCOPE_AGENT);
            if (s >= target) break;   // monotone counters: no false positive
            __builtin_amdgcn_s_sleep(8);
        }
    }
    __syncthreads();
}

// D += A*B in near-fp32 split precision (drop negligible Al*Bl).
__device__ __forceinline__ f32x4 mfma3(half8 ah, half8 al, half8 bh, half8 bl, f32x4 acc) {
    acc = __builtin_amdgcn_mfma_f32_16x16x32_f16(ah, bh, acc, 0, 0, 0);
    acc = __builtin_amdgcn_mfma_f32_16x16x32_f16(al, bh, acc, 0, 0, 0);
    acc = __builtin_amdgcn_mfma_f32_16x16x32_f16(ah, bl, acc, 0, 0, 0);
    return acc;
}

// ---- one 128->128 MLP layer over the block's 48 rows. 12 waves:
// wave w owns row-tile mt = w>>2 and cols [cg*32, cg*32+32), cg = w&3.
// Per-wave chain = 24 MFMA (was 36 at 8 waves); element math identical.
__device__ void layerM(const f16* inHi, const f16* inLo,
                       const f16* Wh, const f16* Wl, const float* bias, bool relu,
                       f16* outHi, f16* outLo, float* gdst, int grow0) {
    const int lane = threadIdx.x & 63, l15 = lane & 15, quad = lane >> 4;
    const int w = threadIdx.x >> 6;          // 0..11
    const int mt = w >> 2, cg = w & 3;
    half8 Bh[2][4], Bl[2][4];
#pragma unroll
    for (int ct = 0; ct < 2; ++ct)
#pragma unroll
        for (int s = 0; s < 4; ++s) {
            size_t off = (size_t)(cg * 32 + ct * 16 + l15) * 128 + s * 32 + quad * 8;
            Bh[ct][s] = *(const half8*)(Wh + off);
            Bl[ct][s] = *(const half8*)(Wl + off);
        }
    float b0 = bias[cg * 32 + l15], b1 = bias[cg * 32 + 16 + l15];
    half8 Ah[4], Al[4];
#pragma unroll
    for (int s = 0; s < 4; ++s) {
        int off = (mt * 16 + l15) * MROW + s * 32 + quad * 8;
        Ah[s] = *(const half8*)(inHi + off);
        Al[s] = *(const half8*)(inLo + off);
    }
    f32x4 acc0 = {0.f, 0.f, 0.f, 0.f}, acc1 = {0.f, 0.f, 0.f, 0.f};
#pragma unroll
    for (int s = 0; s < 4; ++s) {
        acc0 = mfma3(Ah[s], Al[s], Bh[0][s], Bl[0][s], acc0);
        acc1 = mfma3(Ah[s], Al[s], Bh[1][s], Bl[1][s], acc1);
    }
#pragma unroll
    for (int ct = 0; ct < 2; ++ct) {
        f32x4 a = ct ? acc1 : acc0;
        float bb = ct ? b1 : b0;
        int col = cg * 32 + ct * 16 + l15;
#pragma unroll
        for (int reg = 0; reg < 4; ++reg) {
            int row = mt * 16 + quad * 4 + reg;
            float v = a[reg] + bb;
            if (relu) v = fmaxf(v, 0.f);
            if (gdst) {
                __hip_atomic_store(&gdst[(size_t)(grow0 + row) * 128 + col], v,
                                   __ATOMIC_RELAXED, __HIP_MEMORY_SCOPE_AGENT);
            } else {
                f16 hh = (f16)v;
                outHi[row * MROW + col] = hh;
                outLo[row * MROW + col] = (f16)(v - (float)hh);
            }
        }
    }
    __syncthreads();
}

// ---- LSTM over the block's 48 rows: A=[msg;h] (K=256), 512 gate cols.
// Wave w: row-tile mt = w>>2, h-cols [cg*32, cg*32+32) of EACH gate -> acc
// for all 4 gates colocated -> pointwise in-register. A-fragments (one mt)
// hoisted out of the gate loop: 16 ds_reads/wave (was 192 at 8 waves).
__device__ void gatesL(const f16* msgHi, const f16* msgLo, f16* hHi, f16* hLo, float* cF,
                       const f16* Wh, const f16* Wl, const float* bih, const float* bhh) {
    const int lane = threadIdx.x & 63, l15 = lane & 15, quad = lane >> 4;
    const int w = threadIdx.x >> 6;          // 0..11
    const int mt = w >> 2, cg = w & 3;
    half8 Ah[8], Al[8];
#pragma unroll
    for (int s = 0; s < 4; ++s) {
        int off = (mt * 16 + l15) * MROW + s * 32 + quad * 8;
        Ah[s]     = *(const half8*)(msgHi + off);
        Al[s]     = *(const half8*)(msgLo + off);
        Ah[s + 4] = *(const half8*)(hHi + off);
        Al[s + 4] = *(const half8*)(hLo + off);
    }
    f32x4 acc[4][2];
#pragma unroll
    for (int g = 0; g < 4; ++g)
#pragma unroll
        for (int c2 = 0; c2 < 2; ++c2)
            acc[g][c2] = (f32x4){0.f, 0.f, 0.f, 0.f};

    for (int g = 0; g < 4; ++g) {
#pragma unroll
        for (int c2 = 0; c2 < 2; ++c2) {
            half8 Bh[8], Bl[8];
#pragma unroll
            for (int s = 0; s < 8; ++s) {
                size_t off = (size_t)(g * 128 + cg * 32 + c2 * 16 + l15) * 256 + s * 32 + quad * 8;
                Bh[s] = *(const half8*)(Wh + off);
                Bl[s] = *(const half8*)(Wl + off);
            }
#pragma unroll
            for (int s = 0; s < 8; ++s)
                acc[g][c2] = mfma3(Ah[s], Al[s], Bh[s], Bl[s], acc[g][c2]);
        }
    }
    __syncthreads();   // all waves' A-reads of h done before pointwise rewrites h
#pragma unroll
    for (int c2 = 0; c2 < 2; ++c2) {
        int col = cg * 32 + c2 * 16 + l15;
        float gb0 = bih[0 * 128 + col] + bhh[0 * 128 + col];
        float gb1 = bih[1 * 128 + col] + bhh[1 * 128 + col];
        float gb2 = bih[2 * 128 + col] + bhh[2 * 128 + col];
        float gb3 = bih[3 * 128 + col] + bhh[3 * 128 + col];
#pragma unroll
        for (int reg = 0; reg < 4; ++reg) {
            int row = mt * 16 + quad * 4 + reg;
            float gi = acc[0][c2][reg] + gb0;
            float gf = acc[1][c2][reg] + gb1;
            float gg = acc[2][c2][reg] + gb2;
            float go = acc[3][c2][reg] + gb3;
            float cv = cF[row * 128 + col];
            float cn = sigm(gf) * cv + sigm(gi) * tanhf(gg);
            float hn = sigm(go) * tanhf(cn);
            cF[row * 128 + col] = cn;
            f16 hh = (f16)hn;
            hHi[row * MROW + col] = hh;
            hLo[row * MROW + col] = (f16)(hn - (float)hh);
        }
    }
    __syncthreads();
}

// ---- gather helpers: agent-scope 8B loads (bypass non-coherent L2)
__device__ __forceinline__ void ld4q(ull* B, const float* t1g, int idx, int q) {
    const ull* s4 = (const ull*)(t1g + (size_t)idx * 128) + q * 4;
#pragma unroll
    for (int u = 0; u < 4; ++u)
        B[u] = __hip_atomic_load(s4 + u, __ATOMIC_RELAXED, __HIP_MEMORY_SCOPE_AGENT);
}
__device__ __forceinline__ void acc4q(float* a, const ull* B) {
#pragma unroll
    for (int u = 0; u < 4; ++u) {
        union { ull q; float f[2]; } cv; cv.q = B[u];
        a[u * 2 + 0] += cv.f[0];
        a[u * 2 + 1] += cv.f[1];
    }
}

// ---- gather own 48 rows from global t1 into msg planes (hi/lo).
// 16 threads/row x 48 rows = all 768 threads (2x r6 parallelism). 4-deep
// ping-pong pipeline; j-order accumulation per float -> bit-identical.
__device__ void gatherP(const float* t1g, const int* cnt, const int* idxm,
                        f16* msgHi, f16* msgLo, int R0) {
    int r = threadIdx.x >> 4, q = threadIdx.x & 15;   // 8 floats (32B) per thread
    int row = R0 + r;
    int n = cnt[row]; if (n > CAP) n = CAP;
    const int* ir = idxm + (size_t)row * CAP;
    float a[8];
#pragma unroll
    for (int u = 0; u < 8; ++u) a[u] = 0.f;
    ull b0[4], b1[4], b2[4], b3[4];
    if (n > 0) ld4q(b0, t1g, ir[0], q);
    if (n > 1) ld4q(b1, t1g, ir[1], q);
    if (n > 2) ld4q(b2, t1g, ir[2], q);
    if (n > 3) ld4q(b3, t1g, ir[3], q);
    for (int j = 0; j < n; j += 4) {
        acc4q(a, b0);
        if (j + 4 < n) ld4q(b0, t1g, ir[j + 4], q);
        if (j + 1 < n) {
            acc4q(a, b1);
            if (j + 5 < n) ld4q(b1, t1g, ir[j + 5], q);
        }
        if (j + 2 < n) {
            acc4q(a, b2);
            if (j + 6 < n) ld4q(b2, t1g, ir[j + 6], q);
        }
        if (j + 3 < n) {
            acc4q(a, b3);
            if (j + 7 < n) ld4q(b3, t1g, ir[j + 7], q);
        }
    }
#pragma unroll
    for (int u4 = 0; u4 < 2; ++u4) {
        half4v hh, ll;
#pragma unroll
        for (int k = 0; k < 4; ++k) {
            float x = a[u4 * 4 + k];
            f16 h = (f16)x;
            hh[k] = h; ll[k] = (f16)(x - (float)h);
        }
        int off = r * MROW + q * 8 + u4 * 4;
        *(half4v*)(msgHi + off) = hh;
        *(half4v*)(msgLo + off) = ll;
    }
    __syncthreads();
}

// ---------------------------------------------------------------------------
// launch_bounds(768,3): 12 waves = 3/SIMD (1 block/CU, LDS 103KB), VGPR cap
// 170. Naive peak in gatesL ~160+misc; compiler squeezed 176->128 before.
__global__ void __launch_bounds__(TPB, 3) mega(Params p) {
    __shared__ __align__(16) f16 smh[6 * PLANE];       // 78336 B
    __shared__ __align__(16) float cF[RPB * 128];      // 24576 B
    f16 *hHi = smh,             *hLo = smh + PLANE;
    f16 *aHi = smh + 2 * PLANE, *aLo = smh + 3 * PLANE;
    f16 *bHi = smh + 4 * PLANE, *bLo = smh + 5 * PLANE;

    const int R0 = blockIdx.x * RPB;
    const bool isNode = blockIdx.x < NODE_BLKS;

    // init own rows: h0 = vt ? (tw+tb) : (fw+fb); c0 = 0
#pragma unroll
    for (int i = 0; i < (RPB * 128) / TPB; ++i) {
        int e = threadIdx.x + i * TPB;          // 0..6143
        int r = e >> 7, d = e & 127;
        float hv = (p.vt[R0 + r] == 1) ? (p.true_w[d] + p.true_b[d])
                                       : (p.false_w[d] + p.false_b[d]);
        f16 hh = (f16)hv;
        hHi[r * MROW + d] = hh;
        hLo[r * MROW + d] = (f16)(hv - (float)hh);
        cF[r * 128 + d] = 0.f;
    }
    __syncthreads();

    int ep = 0;
    for (int rd = 0; rd < NROUNDS; ++rd) {
        // cm MLP on own rows -> t1a
        layerM(hHi, hLo, p.wm_hi + 0 * 16384, p.wm_lo + 0 * 16384, p.cm_b1, true,  aHi, aLo, nullptr, 0);
        layerM(aHi, aLo, p.wm_hi + 1 * 16384, p.wm_lo + 1 * 16384, p.cm_b2, true,  bHi, bLo, nullptr, 0);
        layerM(bHi, bLo, p.wm_hi + 2 * 16384, p.wm_lo + 2 * 16384, p.cm_b3, false, nullptr, nullptr, p.t1a, R0);
        gsync(p.bar, ++ep * NB);
        if (isNode) {
            gatherP(p.t1a, p.ncnt, p.nidx, aHi, aLo, R0);
            gatesL(aHi, aLo, hHi, hLo, cF, p.vu_hi, p.vu_lo, p.vu_bih, p.vu_bhh);
            // pm MLP on own (node) rows -> t1b
            layerM(hHi, hLo, p.wm_hi + 3 * 16384, p.wm_lo + 3 * 16384, p.pm_b1, true,  aHi, aLo, nullptr, 0);
            layerM(aHi, aLo, p.wm_hi + 4 * 16384, p.wm_lo + 4 * 16384, p.pm_b2, true,  bHi, bLo, nullptr, 0);
            layerM(bHi, bLo, p.wm_hi + 5 * 16384, p.wm_lo + 5 * 16384, p.pm_b3, false, nullptr, nullptr, p.t1b, R0);
        }
        gsync(p.bar, ++ep * NB);
        gatherP(p.t1b, p.vcnt, p.vidx, aHi, aLo, R0);
        gatesL(aHi, aLo, hHi, hLo, cF, p.nu_hi, p.nu_lo, p.nu_bih, p.nu_bhh);
    }

    // vote on leaf blocks (4 threads/row, 32 cols each: same reduction order
    // as all previous verified kernels -> bit-identical output)
    if (!isNode) {
        layerM(hHi, hLo, p.wm_hi + 6 * 16384, p.wm_lo + 6 * 16384, p.vv_b1, true, aHi, aLo, nullptr, 0);
        layerM(aHi, aLo, p.wm_hi + 7 * 16384, p.wm_lo + 7 * 16384, p.vv_b2, true, bHi, bLo, nullptr, 0);
        if (threadIdx.x < 4 * RPB) {
            int r = threadIdx.x >> 2, q = threadIdx.x & 3;
            float s = 0.f;
#pragma unroll
            for (int u = 0; u < 32; ++u) {
                int col = q * 32 + u;
                s += ((float)bHi[r * MROW + col] + (float)bLo[r * MROW + col]) * p.vv_w3[col];
            }
            s += __shfl_xor(s, 1);
            s += __shfl_xor(s, 2);
            if (q == 0) p.out[R0 - NNODES + r] = s + p.vv_b3[0];
        }
    }
}

// ---------------------------------------------------------------------------
__global__ void build_csr(const unsigned int* __restrict__ up,   // fp32 bits
                          int* __restrict__ ncnt, int* __restrict__ nidx,
                          int* __restrict__ vcnt, int* __restrict__ vidx) {
    const int total4 = NNODES * (NVARS / 4);
    const uint4* up4 = (const uint4*)up;
    for (int pidx = blockIdx.x * blockDim.x + threadIdx.x;
         pidx < total4; pidx += gridDim.x * blockDim.x) {
        uint4 w = up4[pidx];
        if ((w.x | w.y | w.z | w.w) == 0u) continue;
        int n  = pidx / (NVARS / 4);
        int v0 = (pidx % (NVARS / 4)) * 4;
        unsigned e[4] = { w.x, w.y, w.z, w.w };
#pragma unroll
        for (int j = 0; j < 4; ++j) {
            if (e[j]) {
                int v = v0 + j;
                int s1 = atomicAdd(&ncnt[n], 1);
                if (s1 < CAP) nidx[n * CAP + s1] = v;
                int s2 = atomicAdd(&vcnt[v], 1);
                if (s2 < CAP) vidx[v * CAP + s2] = n;
            }
        }
    }
}

struct ConvMLP { const float* src[8]; f16 *hi, *lo; };
__global__ void conv_mlp(ConvMLP a) {
    int idx = blockIdx.x * CTPB + threadIdx.x;
    if (idx >= 8 * 16384) return;
    float x = a.src[idx >> 14][idx & 16383];
    f16 h = (f16)x;
    a.hi[idx] = h;
    a.lo[idx] = (f16)(x - (float)h);
}

struct ConvLSTM { const float *wih, *whh; f16 *hi, *lo; };
__global__ void conv_lstm(ConvLSTM a) {
    int idx = blockIdx.x * CTPB + threadIdx.x;
    if (idx >= 512 * 256) return;
    int n = idx >> 8, k = idx & 255;
    float x = (k < 128) ? a.wih[n * 128 + k] : a.whh[n * 128 + (k - 128)];
    f16 h = (f16)x;
    a.hi[idx] = h;
    a.lo[idx] = (f16)(x - (float)h);
}

// ---------------------------------------------------------------------------
extern "C" void kernel_launch(void* const* d_in, const int* in_sizes, int n_in,
                              void* d_out, int out_size, void* d_ws, size_t ws_size,
                              hipStream_t stream) {
    const unsigned int* unpack = (const unsigned int*)d_in[1];

    Params p;
    p.vt      = (const int*)d_in[0];
    p.true_w  = (const float*)d_in[2];
    p.true_b  = (const float*)d_in[3];
    p.false_w = (const float*)d_in[4];
    p.false_b = (const float*)d_in[5];
    p.cm_b1 = (const float*)d_in[7];  p.cm_b2 = (const float*)d_in[9];
    p.cm_b3 = (const float*)d_in[11];
    p.pm_b1 = (const float*)d_in[13]; p.pm_b2 = (const float*)d_in[15];
    p.pm_b3 = (const float*)d_in[17];
    p.vv_b1 = (const float*)d_in[19]; p.vv_b2 = (const float*)d_in[21];
    p.vv_w3 = (const float*)d_in[22]; p.vv_b3 = (const float*)d_in[23];
    p.vu_bih = (const float*)d_in[26]; p.vu_bhh = (const float*)d_in[27];
    p.nu_bih = (const float*)d_in[30]; p.nu_bhh = (const float*)d_in[31];

    // workspace layout
    float* t1a = (float*)d_ws;                   // [12000][128]
    float* t1b = t1a + (size_t)NVARS * 128;      // [12000][128]
    int* ncnt = (int*)(t1b + (size_t)NVARS * 128);
    int* nidx = ncnt + NNODES;                   // [NNODES][CAP]
    int* vcnt = nidx + NNODES * CAP;
    int* vidx = vcnt + NVARS;                    // [NVARS][CAP]
    int* bar  = vidx + NVARS * CAP;              // 8 sharded counters, 64B apart
    uintptr_t wb = (uintptr_t)(bar + 128);
    wb = (wb + 15) & ~(uintptr_t)15;
    f16* wm_hi = (f16*)wb;            // 8*16384
    f16* wm_lo = wm_hi + 131072;
    f16* vu_hi = wm_lo + 131072;      // 512*256
    f16* vu_lo = vu_hi + 131072;
    f16* nu_hi = vu_lo + 131072;
    f16* nu_lo = nu_hi + 131072;

    p.t1a = t1a; p.t1b = t1b; p.bar = bar;
    p.ncnt = ncnt; p.nidx = nidx; p.vcnt = vcnt; p.vidx = vidx;
    p.wm_hi = wm_hi; p.wm_lo = wm_lo;
    p.vu_hi = vu_hi; p.vu_lo = vu_lo; p.nu_hi = nu_hi; p.nu_lo = nu_lo;
    p.out = (float*)d_out;

    (void)hipMemsetAsync(ncnt, 0, NNODES * sizeof(int), stream);
    (void)hipMemsetAsync(vcnt, 0, NVARS * sizeof(int), stream);
    (void)hipMemsetAsync(bar, 0, 128 * sizeof(int), stream);
    build_csr<<<4096, CTPB, 0, stream>>>(unpack, ncnt, nidx, vcnt, vidx);

    ConvMLP cm;
    cm.src[0] = (const float*)d_in[6];  cm.src[1] = (const float*)d_in[8];
    cm.src[2] = (const float*)d_in[10]; cm.src[3] = (const float*)d_in[12];
    cm.src[4] = (const float*)d_in[14]; cm.src[5] = (const float*)d_in[16];
    cm.src[6] = (const float*)d_in[18]; cm.src[7] = (const float*)d_in[20];
    cm.hi = wm_hi; cm.lo = wm_lo;
    conv_mlp<<<512, CTPB, 0, stream>>>(cm);

    ConvLSTM cv; cv.wih = (const float*)d_in[24]; cv.whh = (const float*)d_in[25];
    cv.hi = vu_hi; cv.lo = vu_lo;
    conv_lstm<<<512, CTPB, 0, stream>>>(cv);
    ConvLSTM cn; cn.wih = (const float*)d_in[28]; cn.whh = (const float*)d_in[29];
    cn.hi = nu_hi; cn.lo = nu_lo;
    conv_lstm<<<512, CTPB, 0, stream>>>(cn);

    mega<<<NB, TPB, 0, stream>>>(p);
}

// Round 8
// 1967.271 us; speedup vs baseline: 1.4204x; 1.4204x over previous
//
#include <hip/hip_runtime.h>

#define NVARS    12000
#define NNODES   8400
#define NLEAF    3600
#define NROUNDS  12
#define RPB      48              // rows per block (best weight amortization)
#define NB       250             // blocks (250*48 = 12000; node boundary = 175*48)
#define NODE_BLKS 175
#define CAP      64              // CSR fan-in cap (mean ~10, P(>64) ~ 0)
#define TPB      512             // 8 waves: wave w owns 16 output cols (B loaded once/block)
#define CTPB     256             // helper-kernel block size

typedef _Float16 f16;
typedef _Float16 half8 __attribute__((ext_vector_type(8)));
typedef _Float16 half4v __attribute__((ext_vector_type(4)));
typedef float f32x4 __attribute__((ext_vector_type(4)));
typedef unsigned long long ull;

#define MROW 136                 // LDS plane row stride in halves (272B, 16B-aligned)
#define PLANE (RPB * MROW)       // 6528 halves per plane

struct Params {
    float *t1a, *t1b;
    int *bar;
    const int *vt, *ncnt, *nidx, *vcnt, *vidx;
    const float *true_w, *true_b, *false_w, *false_b;
    const f16 *wm_hi, *wm_lo;          // 8 MLP mats [n=128][k=128] hi/lo
    const f16 *vu_hi, *vu_lo;          // [512][256] (k<128: wih, k>=128: whh)
    const f16 *nu_hi, *nu_lo;
    const float *cm_b1, *cm_b2, *cm_b3, *pm_b1, *pm_b2, *pm_b3;
    const float *vv_b1, *vv_b2, *vv_w3, *vv_b3;
    const float *vu_bih, *vu_bhh, *nu_bih, *nu_bhh;
    float *out;
};

__device__ __forceinline__ float sigm(float x) { return 1.f / (1.f + expf(-x)); }

// ---- software grid barrier, FENCELESS (proven r3: -20%). Sharded arrivals,
// LOAD-only agent-scope spin. vmcnt(0) drain before s_barrier makes all
// agent-scope t1 stores globally visible -> no threadfence, L2 stays
// weight-hot across rounds.
__device__ __forceinline__ void gsync(int* bar, int target) {
    __builtin_amdgcn_s_waitcnt(0);
    __syncthreads();
    if (threadIdx.x == 0) {
        __hip_atomic_fetch_add(&bar[(blockIdx.x & 7) << 4], 1,
                               __ATOMIC_RELAXED, __HIP_MEMORY_SCOPE_AGENT);
        for (;;) {
            int s = 0;
#pragma unroll
            for (int k = 0; k < 8; ++k)
                s += __hip_atomic_load(&bar[k << 4], __ATOMIC_RELAXED,
                                       __HIP_MEMORY_SCOPE_AGENT);
            if (s >= target) break;   // monotone counters: no false positive
            __builtin_amdgcn_s_sleep(8);
        }
    }
    __syncthreads();
}

// D += A*B in near-fp32 split precision (drop negligible Al*Bl).
__device__ __forceinline__ f32x4 mfma3(half8 ah, half8 al, half8 bh, half8 bl, f32x4 acc) {
    acc = __builtin_amdgcn_mfma_f32_16x16x32_f16(ah, bh, acc, 0, 0, 0);
    acc = __builtin_amdgcn_mfma_f32_16x16x32_f16(al, bh, acc, 0, 0, 0);
    acc = __builtin_amdgcn_mfma_f32_16x16x32_f16(ah, bl, acc, 0, 0, 0);
    return acc;
}

// ---- one 128->128 MLP layer over the block's 48 rows. 8 waves: wave w owns
// output cols [w*16, w*16+16). B loaded once/wave, reused across 3 row-tiles.
__device__ void layerM(const f16* inHi, const f16* inLo,
                       const f16* Wh, const f16* Wl, const float* bias, bool relu,
                       f16* outHi, f16* outLo, float* gdst, int grow0) {
    const int lane = threadIdx.x & 63, l15 = lane & 15, quad = lane >> 4;
    const int w = threadIdx.x >> 6;          // 0..7
    half8 Bh[4], Bl[4];
#pragma unroll
    for (int s = 0; s < 4; ++s) {
        size_t off = (size_t)(w * 16 + l15) * 128 + s * 32 + quad * 8;
        Bh[s] = *(const half8*)(Wh + off);
        Bl[s] = *(const half8*)(Wl + off);
    }
    const float b0 = bias[w * 16 + l15];
    const int col = w * 16 + l15;
#pragma unroll
    for (int mt = 0; mt < 3; ++mt) {
        half8 Ah[4], Al[4];
#pragma unroll
        for (int s = 0; s < 4; ++s) {
            int off = (mt * 16 + l15) * MROW + s * 32 + quad * 8;
            Ah[s] = *(const half8*)(inHi + off);
            Al[s] = *(const half8*)(inLo + off);
        }
        f32x4 acc = {0.f, 0.f, 0.f, 0.f};
#pragma unroll
        for (int s = 0; s < 4; ++s)
            acc = mfma3(Ah[s], Al[s], Bh[s], Bl[s], acc);
#pragma unroll
        for (int reg = 0; reg < 4; ++reg) {
            int row = mt * 16 + quad * 4 + reg;
            float v = acc[reg] + b0;
            if (relu) v = fmaxf(v, 0.f);
            if (gdst) {
                __hip_atomic_store(&gdst[(size_t)(grow0 + row) * 128 + col], v,
                                   __ATOMIC_RELAXED, __HIP_MEMORY_SCOPE_AGENT);
            } else {
                f16 hh = (f16)v;
                outHi[row * MROW + col] = hh;
                outLo[row * MROW + col] = (f16)(v - (float)hh);
            }
        }
    }
    __syncthreads();
}

// ---- LSTM over the block's 48 rows: A=[msg;h] (K=256), 512 gate cols.
// Wave w owns h-cols [w*16,w*16+16) of EACH gate -> pointwise in-register.
// K-quarter loop (K=64/iter): B for ALL 4 gates held (16 half8 = 64 VGPR),
// A loaded once per (kq, mt) -> A-LDS reads 192->48 half8/wave (4x cut) with
// B still loaded exactly once/block. Accumulation order per acc[mt][g] is
// kq0..3 x s0..1 == old s0..7 -> bit-identical.
__device__ void gatesL(const f16* msgHi, const f16* msgLo, f16* hHi, f16* hLo, float* cF,
                       const f16* Wh, const f16* Wl, const float* bih, const float* bhh) {
    const int lane = threadIdx.x & 63, l15 = lane & 15, quad = lane >> 4;
    const int w = threadIdx.x >> 6;          // 0..7
    float gb[4];
#pragma unroll
    for (int g = 0; g < 4; ++g)
        gb[g] = bih[g * 128 + w * 16 + l15] + bhh[g * 128 + w * 16 + l15];
    f32x4 acc[3][4];
#pragma unroll
    for (int mt = 0; mt < 3; ++mt)
#pragma unroll
        for (int g = 0; g < 4; ++g)
            acc[mt][g] = (f32x4){0.f, 0.f, 0.f, 0.f};

#pragma unroll
    for (int kq = 0; kq < 4; ++kq) {         // K-quarter: kq<2 = msg, kq>=2 = h
        half8 Bh[4][2], Bl[4][2];
#pragma unroll
        for (int g = 0; g < 4; ++g)
#pragma unroll
            for (int s = 0; s < 2; ++s) {
                size_t off = (size_t)(g * 128 + w * 16 + l15) * 256
                           + kq * 64 + s * 32 + quad * 8;
                Bh[g][s] = *(const half8*)(Wh + off);
                Bl[g][s] = *(const half8*)(Wl + off);
            }
        const f16* aHiP = (kq < 2) ? msgHi : hHi;
        const f16* aLoP = (kq < 2) ? msgLo : hLo;
        const int kqo = (kq & 1) * 64;
#pragma unroll
        for (int mt = 0; mt < 3; ++mt) {
            half8 Ah[2], Al[2];
#pragma unroll
            for (int s = 0; s < 2; ++s) {
                int off = (mt * 16 + l15) * MROW + kqo + s * 32 + quad * 8;
                Ah[s] = *(const half8*)(aHiP + off);
                Al[s] = *(const half8*)(aLoP + off);
            }
#pragma unroll
            for (int g = 0; g < 4; ++g)
#pragma unroll
                for (int s = 0; s < 2; ++s)
                    acc[mt][g] = mfma3(Ah[s], Al[s], Bh[g][s], Bl[g][s], acc[mt][g]);
        }
    }
    __syncthreads();   // all waves' A-reads of h done before pointwise rewrites h
    const int col = w * 16 + l15;
#pragma unroll
    for (int mt = 0; mt < 3; ++mt) {
#pragma unroll
        for (int reg = 0; reg < 4; ++reg) {
            int row = mt * 16 + quad * 4 + reg;
            float gi = acc[mt][0][reg] + gb[0];
            float gf = acc[mt][1][reg] + gb[1];
            float gg = acc[mt][2][reg] + gb[2];
            float go = acc[mt][3][reg] + gb[3];
            float cv = cF[row * 128 + col];
            float cn = sigm(gf) * cv + sigm(gi) * tanhf(gg);
            float hn = sigm(go) * tanhf(cn);
            cF[row * 128 + col] = cn;
            f16 hh = (f16)hn;
            hHi[row * MROW + col] = hh;
            hLo[row * MROW + col] = (f16)(hn - (float)hh);
        }
    }
    __syncthreads();
}

// ---- gather helpers: agent-scope 8B loads (bypass non-coherent L2)
__device__ __forceinline__ void ld8(ull* B, const float* t1g, int idx, int q) {
    const ull* s8 = (const ull*)(t1g + (size_t)idx * 128) + q * 8;
#pragma unroll
    for (int u = 0; u < 8; ++u)
        B[u] = __hip_atomic_load(s8 + u, __ATOMIC_RELAXED, __HIP_MEMORY_SCOPE_AGENT);
}
__device__ __forceinline__ void acc8(float* a, const ull* B) {
#pragma unroll
    for (int u = 0; u < 8; ++u) {
        union { ull q; float f[2]; } cv; cv.q = B[u];
        a[u * 2 + 0] += cv.f[0];
        a[u * 2 + 1] += cv.f[1];
    }
}

// ---- gather own 48 rows from global t1 into msg planes (hi/lo).
// 8 threads/row x 48 rows = 384 of 512 threads. 4-deep ping-pong pipeline,
// j-order accumulation (bit-identical to serial).
__device__ void gatherP(const float* t1g, const int* cnt, const int* idxm,
                        f16* msgHi, f16* msgLo, int R0) {
    if (threadIdx.x < 8 * RPB) {
        int r = threadIdx.x >> 3, q = threadIdx.x & 7;
        int row = R0 + r;
        int n = cnt[row]; if (n > CAP) n = CAP;
        const int* ir = idxm + (size_t)row * CAP;
        float a[16];
#pragma unroll
        for (int u = 0; u < 16; ++u) a[u] = 0.f;
        ull b0[8], b1[8], b2[8], b3[8];
        if (n > 0) ld8(b0, t1g, ir[0], q);
        if (n > 1) ld8(b1, t1g, ir[1], q);
        if (n > 2) ld8(b2, t1g, ir[2], q);
        if (n > 3) ld8(b3, t1g, ir[3], q);
        for (int j = 0; j < n; j += 4) {
            acc8(a, b0);
            if (j + 4 < n) ld8(b0, t1g, ir[j + 4], q);
            if (j + 1 < n) {
                acc8(a, b1);
                if (j + 5 < n) ld8(b1, t1g, ir[j + 5], q);
            }
            if (j + 2 < n) {
                acc8(a, b2);
                if (j + 6 < n) ld8(b2, t1g, ir[j + 6], q);
            }
            if (j + 3 < n) {
                acc8(a, b3);
                if (j + 7 < n) ld8(b3, t1g, ir[j + 7], q);
            }
        }
#pragma unroll
        for (int u4 = 0; u4 < 4; ++u4) {
            half4v hh, ll;
#pragma unroll
            for (int k = 0; k < 4; ++k) {
                float x = a[u4 * 4 + k];
                f16 h = (f16)x;
                hh[k] = h; ll[k] = (f16)(x - (float)h);
            }
            int off = r * MROW + q * 16 + u4 * 4;
            *(half4v*)(msgHi + off) = hh;
            *(half4v*)(msgLo + off) = ll;
        }
    }
    __syncthreads();
}

// ---------------------------------------------------------------------------
// launch_bounds(512,1): 1 block/CU, 8 waves (2/SIMD), 256-VGPR budget.
// NB=250 <= 256 CUs -> co-resident, grid barrier safe.
__global__ void __launch_bounds__(TPB, 1) mega(Params p) {
    __shared__ __align__(16) f16 smh[6 * PLANE];       // 78336 B
    __shared__ __align__(16) float cF[RPB * 128];      // 24576 B
    f16 *hHi = smh,             *hLo = smh + PLANE;
    f16 *aHi = smh + 2 * PLANE, *aLo = smh + 3 * PLANE;
    f16 *bHi = smh + 4 * PLANE, *bLo = smh + 5 * PLANE;

    const int R0 = blockIdx.x * RPB;
    const bool isNode = blockIdx.x < NODE_BLKS;

    // init own rows: h0 = vt ? (tw+tb) : (fw+fb); c0 = 0
#pragma unroll
    for (int i = 0; i < (RPB * 128) / TPB; ++i) {
        int e = threadIdx.x + i * TPB;          // 0..6143
        int r = e >> 7, d = e & 127;
        float hv = (p.vt[R0 + r] == 1) ? (p.true_w[d] + p.true_b[d])
                                       : (p.false_w[d] + p.false_b[d]);
        f16 hh = (f16)hv;
        hHi[r * MROW + d] = hh;
        hLo[r * MROW + d] = (f16)(hv - (float)hh);
        cF[r * 128 + d] = 0.f;
    }
    __syncthreads();

    int ep = 0;
    for (int rd = 0; rd < NROUNDS; ++rd) {
        // cm MLP on own rows -> t1a
        layerM(hHi, hLo, p.wm_hi + 0 * 16384, p.wm_lo + 0 * 16384, p.cm_b1, true,  aHi, aLo, nullptr, 0);
        layerM(aHi, aLo, p.wm_hi + 1 * 16384, p.wm_lo + 1 * 16384, p.cm_b2, true,  bHi, bLo, nullptr, 0);
        layerM(bHi, bLo, p.wm_hi + 2 * 16384, p.wm_lo + 2 * 16384, p.cm_b3, false, nullptr, nullptr, p.t1a, R0);
        gsync(p.bar, ++ep * NB);
        if (isNode) {
            gatherP(p.t1a, p.ncnt, p.nidx, aHi, aLo, R0);
            gatesL(aHi, aLo, hHi, hLo, cF, p.vu_hi, p.vu_lo, p.vu_bih, p.vu_bhh);
            // pm MLP on own (node) rows -> t1b
            layerM(hHi, hLo, p.wm_hi + 3 * 16384, p.wm_lo + 3 * 16384, p.pm_b1, true,  aHi, aLo, nullptr, 0);
            layerM(aHi, aLo, p.wm_hi + 4 * 16384, p.wm_lo + 4 * 16384, p.pm_b2, true,  bHi, bLo, nullptr, 0);
            layerM(bHi, bLo, p.wm_hi + 5 * 16384, p.wm_lo + 5 * 16384, p.pm_b3, false, nullptr, nullptr, p.t1b, R0);
        }
        gsync(p.bar, ++ep * NB);
        gatherP(p.t1b, p.vcnt, p.vidx, aHi, aLo, R0);
        gatesL(aHi, aLo, hHi, hLo, cF, p.nu_hi, p.nu_lo, p.nu_bih, p.nu_bhh);
    }

    // vote on leaf blocks (4 threads/row, 32 cols each: same reduction order
    // as all previous verified kernels -> bit-identical output)
    if (!isNode) {
        layerM(hHi, hLo, p.wm_hi + 6 * 16384, p.wm_lo + 6 * 16384, p.vv_b1, true, aHi, aLo, nullptr, 0);
        layerM(aHi, aLo, p.wm_hi + 7 * 16384, p.wm_lo + 7 * 16384, p.vv_b2, true, bHi, bLo, nullptr, 0);
        if (threadIdx.x < 4 * RPB) {
            int r = threadIdx.x >> 2, q = threadIdx.x & 3;
            float s = 0.f;
#pragma unroll
            for (int u = 0; u < 32; ++u) {
                int col = q * 32 + u;
                s += ((float)bHi[r * MROW + col] + (float)bLo[r * MROW + col]) * p.vv_w3[col];
            }
            s += __shfl_xor(s, 1);
            s += __shfl_xor(s, 2);
            if (q == 0) p.out[R0 - NNODES + r] = s + p.vv_b3[0];
        }
    }
}

// ---------------------------------------------------------------------------
__global__ void build_csr(const unsigned int* __restrict__ up,   // fp32 bits
                          int* __restrict__ ncnt, int* __restrict__ nidx,
                          int* __restrict__ vcnt, int* __restrict__ vidx) {
    const int total4 = NNODES * (NVARS / 4);
    const uint4* up4 = (const uint4*)up;
    for (int pidx = blockIdx.x * blockDim.x + threadIdx.x;
         pidx < total4; pidx += gridDim.x * blockDim.x) {
        uint4 w = up4[pidx];
        if ((w.x | w.y | w.z | w.w) == 0u) continue;
        int n  = pidx / (NVARS / 4);
        int v0 = (pidx % (NVARS / 4)) * 4;
        unsigned e[4] = { w.x, w.y, w.z, w.w };
#pragma unroll
        for (int j = 0; j < 4; ++j) {
            if (e[j]) {
                int v = v0 + j;
                int s1 = atomicAdd(&ncnt[n], 1);
                if (s1 < CAP) nidx[n * CAP + s1] = v;
                int s2 = atomicAdd(&vcnt[v], 1);
                if (s2 < CAP) vidx[v * CAP + s2] = n;
            }
        }
    }
}

struct ConvMLP { const float* src[8]; f16 *hi, *lo; };
__global__ void conv_mlp(ConvMLP a) {
    int idx = blockIdx.x * CTPB + threadIdx.x;
    if (idx >= 8 * 16384) return;
    float x = a.src[idx >> 14][idx & 16383];
    f16 h = (f16)x;
    a.hi[idx] = h;
    a.lo[idx] = (f16)(x - (float)h);
}

struct ConvLSTM { const float *wih, *whh; f16 *hi, *lo; };
__global__ void conv_lstm(ConvLSTM a) {
    int idx = blockIdx.x * CTPB + threadIdx.x;
    if (idx >= 512 * 256) return;
    int n = idx >> 8, k = idx & 255;
    float x = (k < 128) ? a.wih[n * 128 + k] : a.whh[n * 128 + (k - 128)];
    f16 h = (f16)x;
    a.hi[idx] = h;
    a.lo[idx] = (f16)(x - (float)h);
}

// ---------------------------------------------------------------------------
extern "C" void kernel_launch(void* const* d_in, const int* in_sizes, int n_in,
                              void* d_out, int out_size, void* d_ws, size_t ws_size,
                              hipStream_t stream) {
    const unsigned int* unpack = (const unsigned int*)d_in[1];

    Params p;
    p.vt      = (const int*)d_in[0];
    p.true_w  = (const float*)d_in[2];
    p.true_b  = (const float*)d_in[3];
    p.false_w = (const float*)d_in[4];
    p.false_b = (const float*)d_in[5];
    p.cm_b1 = (const float*)d_in[7];  p.cm_b2 = (const float*)d_in[9];
    p.cm_b3 = (const float*)d_in[11];
    p.pm_b1 = (const float*)d_in[13]; p.pm_b2 = (const float*)d_in[15];
    p.pm_b3 = (const float*)d_in[17];
    p.vv_b1 = (const float*)d_in[19]; p.vv_b2 = (const float*)d_in[21];
    p.vv_w3 = (const float*)d_in[22]; p.vv_b3 = (const float*)d_in[23];
    p.vu_bih = (const float*)d_in[26]; p.vu_bhh = (const float*)d_in[27];
    p.nu_bih = (const float*)d_in[30]; p.nu_bhh = (const float*)d_in[31];

    // workspace layout
    float* t1a = (float*)d_ws;                   // [12000][128]
    float* t1b = t1a + (size_t)NVARS * 128;      // [12000][128]
    int* ncnt = (int*)(t1b + (size_t)NVARS * 128);
    int* nidx = ncnt + NNODES;                   // [NNODES][CAP]
    int* vcnt = nidx + NNODES * CAP;
    int* vidx = vcnt + NVARS;                    // [NVARS][CAP]
    int* bar  = vidx + NVARS * CAP;              // 8 sharded counters, 64B apart
    uintptr_t wb = (uintptr_t)(bar + 128);
    wb = (wb + 15) & ~(uintptr_t)15;
    f16* wm_hi = (f16*)wb;            // 8*16384
    f16* wm_lo = wm_hi + 131072;
    f16* vu_hi = wm_lo + 131072;      // 512*256
    f16* vu_lo = vu_hi + 131072;
    f16* nu_hi = vu_lo + 131072;
    f16* nu_lo = nu_hi + 131072;

    p.t1a = t1a; p.t1b = t1b; p.bar = bar;
    p.ncnt = ncnt; p.nidx = nidx; p.vcnt = vcnt; p.vidx = vidx;
    p.wm_hi = wm_hi; p.wm_lo = wm_lo;
    p.vu_hi = vu_hi; p.vu_lo = vu_lo; p.nu_hi = nu_hi; p.nu_lo = nu_lo;
    p.out = (float*)d_out;

    (void)hipMemsetAsync(ncnt, 0, NNODES * sizeof(int), stream);
    (void)hipMemsetAsync(vcnt, 0, NVARS * sizeof(int), stream);
    (void)hipMemsetAsync(bar, 0, 128 * sizeof(int), stream);
    build_csr<<<4096, CTPB, 0, stream>>>(unpack, ncnt, nidx, vcnt, vidx);

    ConvMLP cm;
    cm.src[0] = (const float*)d_in[6];  cm.src[1] = (const float*)d_in[8];
    cm.src[2] = (const float*)d_in[10]; cm.src[3] = (const float*)d_in[12];
    cm.src[4] = (const float*)d_in[14]; cm.src[5] = (const float*)d_in[16];
    cm.src[6] = (const float*)d_in[18]; cm.src[7] = (const float*)d_in[20];
    cm.hi = wm_hi; cm.lo = wm_lo;
    conv_mlp<<<512, CTPB, 0, stream>>>(cm);

    ConvLSTM cv; cv.wih = (const float*)d_in[24]; cv.whh = (const float*)d_in[25];
    cv.hi = vu_hi; cv.lo = vu_lo;
    conv_lstm<<<512, CTPB, 0, stream>>>(cv);
    ConvLSTM cn; cn.wih = (const float*)d_in[28]; cn.whh = (const float*)d_in[29];
    cn.hi = nu_hi; cn.lo = nu_lo;
    conv_lstm<<<512, CTPB, 0, stream>>>(cn);

    mega<<<NB, TPB, 0, stream>>>(p);
}

// Round 9
// 1713.213 us; speedup vs baseline: 1.6311x; 1.1483x over previous
//
#include <hip/hip_runtime.h>

#define NVARS    12000
#define NNODES   8400
#define NLEAF    3600
#define NROUNDS  12
#define RPB      48              // rows per block (best weight amortization)
#define NB       250             // blocks (250*48 = 12000; node boundary = 175*48)
#define NODE_BLKS 175
#define CAP      64              // CSR fan-in cap (mean ~10, P(>64) ~ 0)
#define TPB      512             // 8 waves: wave w owns 16 output cols (B loaded once/block)
#define CTPB     256             // helper-kernel block size

typedef _Float16 f16;
typedef _Float16 half8 __attribute__((ext_vector_type(8)));
typedef _Float16 half4v __attribute__((ext_vector_type(4)));
typedef float f32x4 __attribute__((ext_vector_type(4)));
typedef unsigned long long ull;

#define MROW 136                 // LDS plane row stride in halves (272B, 16B-aligned)
#define PLANE (RPB * MROW)       // 6528 halves per plane

struct Params {
    float *t1a, *t1b;
    int *bar;
    const int *vt, *ncnt, *nidx, *vcnt, *vidx;
    const float *true_w, *true_b, *false_w, *false_b;
    const f16 *wm_hi, *wm_lo;          // 8 MLP mats [n=128][k=128] (lo now unused)
    const f16 *vu_hi, *vu_lo;          // [512][256] (k<128: wih, k>=128: whh)
    const f16 *nu_hi, *nu_lo;
    const float *cm_b1, *cm_b2, *cm_b3, *pm_b1, *pm_b2, *pm_b3;
    const float *vv_b1, *vv_b2, *vv_w3, *vv_b3;
    const float *vu_bih, *vu_bhh, *nu_bih, *nu_bhh;
    float *out;
};

__device__ __forceinline__ float sigm(float x) { return 1.f / (1.f + expf(-x)); }

// ---- software grid barrier, FENCELESS (proven r3: -20%). Sharded arrivals,
// LOAD-only agent-scope spin; s_sleep(2) for tight release detection.
__device__ __forceinline__ void gsync(int* bar, int target) {
    __builtin_amdgcn_s_waitcnt(0);
    __syncthreads();
    if (threadIdx.x == 0) {
        __hip_atomic_fetch_add(&bar[(blockIdx.x & 7) << 4], 1,
                               __ATOMIC_RELAXED, __HIP_MEMORY_SCOPE_AGENT);
        for (;;) {
            int s = 0;
#pragma unroll
            for (int k = 0; k < 8; ++k)
                s += __hip_atomic_load(&bar[k << 4], __ATOMIC_RELAXED,
                                       __HIP_MEMORY_SCOPE_AGENT);
            if (s >= target) break;   // monotone counters: no false positive
            __builtin_amdgcn_s_sleep(2);
        }
    }
    __syncthreads();
}

// D += A*B, A in hi/lo split (near-fp32 activations), B plain fp16 weights.
// (B-lo term dropped: weight-rounding-only error ~2^-11 rel; halves the
// weight stream from L2 and cuts MFMA count by 1/3.)
__device__ __forceinline__ f32x4 mfma2(half8 ah, half8 al, half8 bh, f32x4 acc) {
    acc = __builtin_amdgcn_mfma_f32_16x16x32_f16(ah, bh, acc, 0, 0, 0);
    acc = __builtin_amdgcn_mfma_f32_16x16x32_f16(al, bh, acc, 0, 0, 0);
    return acc;
}

// ---- one 128->128 MLP layer over the block's 48 rows. 8 waves: wave w owns
// output cols [w*16, w*16+16). B loaded once/wave, reused across 3 row-tiles.
__device__ void layerM(const f16* inHi, const f16* inLo,
                       const f16* Wh, const float* bias, bool relu,
                       f16* outHi, f16* outLo, float* gdst, int grow0) {
    const int lane = threadIdx.x & 63, l15 = lane & 15, quad = lane >> 4;
    const int w = threadIdx.x >> 6;          // 0..7
    half8 Bh[4];
#pragma unroll
    for (int s = 0; s < 4; ++s) {
        size_t off = (size_t)(w * 16 + l15) * 128 + s * 32 + quad * 8;
        Bh[s] = *(const half8*)(Wh + off);
    }
    const float b0 = bias[w * 16 + l15];
    const int col = w * 16 + l15;
#pragma unroll
    for (int mt = 0; mt < 3; ++mt) {
        half8 Ah[4], Al[4];
#pragma unroll
        for (int s = 0; s < 4; ++s) {
            int off = (mt * 16 + l15) * MROW + s * 32 + quad * 8;
            Ah[s] = *(const half8*)(inHi + off);
            Al[s] = *(const half8*)(inLo + off);
        }
        f32x4 acc = {0.f, 0.f, 0.f, 0.f};
#pragma unroll
        for (int s = 0; s < 4; ++s)
            acc = mfma2(Ah[s], Al[s], Bh[s], acc);
#pragma unroll
        for (int reg = 0; reg < 4; ++reg) {
            int row = mt * 16 + quad * 4 + reg;
            float v = acc[reg] + b0;
            if (relu) v = fmaxf(v, 0.f);
            if (gdst) {
                __hip_atomic_store(&gdst[(size_t)(grow0 + row) * 128 + col], v,
                                   __ATOMIC_RELAXED, __HIP_MEMORY_SCOPE_AGENT);
            } else {
                f16 hh = (f16)v;
                outHi[row * MROW + col] = hh;
                outLo[row * MROW + col] = (f16)(v - (float)hh);
            }
        }
    }
    __syncthreads();
}

// ---- LSTM over the block's 48 rows: A=[msg;h] (K=256), 512 gate cols.
// Wave w owns h-cols [w*16,w*16+16) of EACH gate -> pointwise in-register.
// Structure identical to the proven r6 kernel, minus the B-lo plane.
__device__ void gatesL(const f16* msgHi, const f16* msgLo, f16* hHi, f16* hLo, float* cF,
                       const f16* Wh, const float* bih, const float* bhh) {
    const int lane = threadIdx.x & 63, l15 = lane & 15, quad = lane >> 4;
    const int w = threadIdx.x >> 6;          // 0..7
    float gb[4];
#pragma unroll
    for (int g = 0; g < 4; ++g)
        gb[g] = bih[g * 128 + w * 16 + l15] + bhh[g * 128 + w * 16 + l15];
    f32x4 acc[3][4];
#pragma unroll
    for (int mt = 0; mt < 3; ++mt)
#pragma unroll
        for (int g = 0; g < 4; ++g)
            acc[mt][g] = (f32x4){0.f, 0.f, 0.f, 0.f};

    for (int g = 0; g < 4; ++g) {
        half8 Bh[8];
#pragma unroll
        for (int s = 0; s < 8; ++s) {
            size_t off = (size_t)(g * 128 + w * 16 + l15) * 256 + s * 32 + quad * 8;
            Bh[s] = *(const half8*)(Wh + off);
        }
#pragma unroll
        for (int mt = 0; mt < 3; ++mt) {
            half8 Ah[8], Al[8];
#pragma unroll
            for (int s = 0; s < 4; ++s) {
                int off = (mt * 16 + l15) * MROW + s * 32 + quad * 8;
                Ah[s]     = *(const half8*)(msgHi + off);
                Al[s]     = *(const half8*)(msgLo + off);
                Ah[s + 4] = *(const half8*)(hHi + off);
                Al[s + 4] = *(const half8*)(hLo + off);
            }
#pragma unroll
            for (int s = 0; s < 8; ++s)
                acc[mt][g] = mfma2(Ah[s], Al[s], Bh[s], acc[mt][g]);
        }
    }
    __syncthreads();   // all waves' A-reads of h done before pointwise rewrites h
    const int col = w * 16 + l15;
#pragma unroll
    for (int mt = 0; mt < 3; ++mt) {
#pragma unroll
        for (int reg = 0; reg < 4; ++reg) {
            int row = mt * 16 + quad * 4 + reg;
            float gi = acc[mt][0][reg] + gb[0];
            float gf = acc[mt][1][reg] + gb[1];
            float gg = acc[mt][2][reg] + gb[2];
            float go = acc[mt][3][reg] + gb[3];
            float cv = cF[row * 128 + col];
            float cn = sigm(gf) * cv + sigm(gi) * tanhf(gg);
            float hn = sigm(go) * tanhf(cn);
            cF[row * 128 + col] = cn;
            f16 hh = (f16)hn;
            hHi[row * MROW + col] = hh;
            hLo[row * MROW + col] = (f16)(hn - (float)hh);
        }
    }
    __syncthreads();
}

// ---- gather helpers: agent-scope 8B loads (bypass non-coherent L2)
__device__ __forceinline__ void ld8(ull* B, const float* t1g, int idx, int q) {
    const ull* s8 = (const ull*)(t1g + (size_t)idx * 128) + q * 8;
#pragma unroll
    for (int u = 0; u < 8; ++u)
        B[u] = __hip_atomic_load(s8 + u, __ATOMIC_RELAXED, __HIP_MEMORY_SCOPE_AGENT);
}
__device__ __forceinline__ void acc8(float* a, const ull* B) {
#pragma unroll
    for (int u = 0; u < 8; ++u) {
        union { ull q; float f[2]; } cv; cv.q = B[u];
        a[u * 2 + 0] += cv.f[0];
        a[u * 2 + 1] += cv.f[1];
    }
}

// ---- gather own 48 rows from global t1 into msg planes (hi/lo).
// 8 threads/row x 48 rows = 384 of 512 threads. 4-deep ping-pong pipeline,
// j-order accumulation (bit-identical to serial).
__device__ void gatherP(const float* t1g, const int* cnt, const int* idxm,
                        f16* msgHi, f16* msgLo, int R0) {
    if (threadIdx.x < 8 * RPB) {
        int r = threadIdx.x >> 3, q = threadIdx.x & 7;
        int row = R0 + r;
        int n = cnt[row]; if (n > CAP) n = CAP;
        const int* ir = idxm + (size_t)row * CAP;
        float a[16];
#pragma unroll
        for (int u = 0; u < 16; ++u) a[u] = 0.f;
        ull b0[8], b1[8], b2[8], b3[8];
        if (n > 0) ld8(b0, t1g, ir[0], q);
        if (n > 1) ld8(b1, t1g, ir[1], q);
        if (n > 2) ld8(b2, t1g, ir[2], q);
        if (n > 3) ld8(b3, t1g, ir[3], q);
        for (int j = 0; j < n; j += 4) {
            acc8(a, b0);
            if (j + 4 < n) ld8(b0, t1g, ir[j + 4], q);
            if (j + 1 < n) {
                acc8(a, b1);
                if (j + 5 < n) ld8(b1, t1g, ir[j + 5], q);
            }
            if (j + 2 < n) {
                acc8(a, b2);
                if (j + 6 < n) ld8(b2, t1g, ir[j + 6], q);
            }
            if (j + 3 < n) {
                acc8(a, b3);
                if (j + 7 < n) ld8(b3, t1g, ir[j + 7], q);
            }
        }
#pragma unroll
        for (int u4 = 0; u4 < 4; ++u4) {
            half4v hh, ll;
#pragma unroll
            for (int k = 0; k < 4; ++k) {
                float x = a[u4 * 4 + k];
                f16 h = (f16)x;
                hh[k] = h; ll[k] = (f16)(x - (float)h);
            }
            int off = r * MROW + q * 16 + u4 * 4;
            *(half4v*)(msgHi + off) = hh;
            *(half4v*)(msgLo + off) = ll;
        }
    }
    __syncthreads();
}

// ---------------------------------------------------------------------------
// launch_bounds(512,1): 1 block/CU, 8 waves (2/SIMD), 256-VGPR budget.
// NB=250 <= 256 CUs -> co-resident, grid barrier safe.
__global__ void __launch_bounds__(TPB, 1) mega(Params p) {
    __shared__ __align__(16) f16 smh[6 * PLANE];       // 78336 B
    __shared__ __align__(16) float cF[RPB * 128];      // 24576 B
    f16 *hHi = smh,             *hLo = smh + PLANE;
    f16 *aHi = smh + 2 * PLANE, *aLo = smh + 3 * PLANE;
    f16 *bHi = smh + 4 * PLANE, *bLo = smh + 5 * PLANE;

    const int R0 = blockIdx.x * RPB;
    const bool isNode = blockIdx.x < NODE_BLKS;

    // init own rows: h0 = vt ? (tw+tb) : (fw+fb); c0 = 0
#pragma unroll
    for (int i = 0; i < (RPB * 128) / TPB; ++i) {
        int e = threadIdx.x + i * TPB;          // 0..6143
        int r = e >> 7, d = e & 127;
        float hv = (p.vt[R0 + r] == 1) ? (p.true_w[d] + p.true_b[d])
                                       : (p.false_w[d] + p.false_b[d]);
        f16 hh = (f16)hv;
        hHi[r * MROW + d] = hh;
        hLo[r * MROW + d] = (f16)(hv - (float)hh);
        cF[r * 128 + d] = 0.f;
    }
    __syncthreads();

    int ep = 0;
    for (int rd = 0; rd < NROUNDS; ++rd) {
        // cm MLP on own rows -> t1a
        layerM(hHi, hLo, p.wm_hi + 0 * 16384, p.cm_b1, true,  aHi, aLo, nullptr, 0);
        layerM(aHi, aLo, p.wm_hi + 1 * 16384, p.cm_b2, true,  bHi, bLo, nullptr, 0);
        layerM(bHi, bLo, p.wm_hi + 2 * 16384, p.cm_b3, false, nullptr, nullptr, p.t1a, R0);
        gsync(p.bar, ++ep * NB);
        if (isNode) {
            gatherP(p.t1a, p.ncnt, p.nidx, aHi, aLo, R0);
            gatesL(aHi, aLo, hHi, hLo, cF, p.vu_hi, p.vu_bih, p.vu_bhh);
            // pm MLP on own (node) rows -> t1b
            layerM(hHi, hLo, p.wm_hi + 3 * 16384, p.pm_b1, true,  aHi, aLo, nullptr, 0);
            layerM(aHi, aLo, p.wm_hi + 4 * 16384, p.pm_b2, true,  bHi, bLo, nullptr, 0);
            layerM(bHi, bLo, p.wm_hi + 5 * 16384, p.pm_b3, false, nullptr, nullptr, p.t1b, R0);
        }
        gsync(p.bar, ++ep * NB);
        gatherP(p.t1b, p.vcnt, p.vidx, aHi, aLo, R0);
        gatesL(aHi, aLo, hHi, hLo, cF, p.nu_hi, p.nu_bih, p.nu_bhh);
    }

    // vote on leaf blocks (4 threads/row, 32 cols each: same reduction order
    // as all previous verified kernels)
    if (!isNode) {
        layerM(hHi, hLo, p.wm_hi + 6 * 16384, p.vv_b1, true, aHi, aLo, nullptr, 0);
        layerM(aHi, aLo, p.wm_hi + 7 * 16384, p.vv_b2, true, bHi, bLo, nullptr, 0);
        if (threadIdx.x < 4 * RPB) {
            int r = threadIdx.x >> 2, q = threadIdx.x & 3;
            float s = 0.f;
#pragma unroll
            for (int u = 0; u < 32; ++u) {
                int col = q * 32 + u;
                s += ((float)bHi[r * MROW + col] + (float)bLo[r * MROW + col]) * p.vv_w3[col];
            }
            s += __shfl_xor(s, 1);
            s += __shfl_xor(s, 2);
            if (q == 0) p.out[R0 - NNODES + r] = s + p.vv_b3[0];
        }
    }
}

// ---------------------------------------------------------------------------
__global__ void build_csr(const unsigned int* __restrict__ up,   // fp32 bits
                          int* __restrict__ ncnt, int* __restrict__ nidx,
                          int* __restrict__ vcnt, int* __restrict__ vidx) {
    const int total4 = NNODES * (NVARS / 4);
    const uint4* up4 = (const uint4*)up;
    for (int pidx = blockIdx.x * blockDim.x + threadIdx.x;
         pidx < total4; pidx += gridDim.x * blockDim.x) {
        uint4 w = up4[pidx];
        if ((w.x | w.y | w.z | w.w) == 0u) continue;
        int n  = pidx / (NVARS / 4);
        int v0 = (pidx % (NVARS / 4)) * 4;
        unsigned e[4] = { w.x, w.y, w.z, w.w };
#pragma unroll
        for (int j = 0; j < 4; ++j) {
            if (e[j]) {
                int v = v0 + j;
                int s1 = atomicAdd(&ncnt[n], 1);
                if (s1 < CAP) nidx[n * CAP + s1] = v;
                int s2 = atomicAdd(&vcnt[v], 1);
                if (s2 < CAP) vidx[v * CAP + s2] = n;
            }
        }
    }
}

struct ConvMLP { const float* src[8]; f16 *hi, *lo; };
__global__ void conv_mlp(ConvMLP a) {
    int idx = blockIdx.x * CTPB + threadIdx.x;
    if (idx >= 8 * 16384) return;
    float x = a.src[idx >> 14][idx & 16383];
    f16 h = (f16)x;
    a.hi[idx] = h;
    a.lo[idx] = (f16)(x - (float)h);
}

struct ConvLSTM { const float *wih, *whh; f16 *hi, *lo; };
__global__ void conv_lstm(ConvLSTM a) {
    int idx = blockIdx.x * CTPB + threadIdx.x;
    if (idx >= 512 * 256) return;
    int n = idx >> 8, k = idx & 255;
    float x = (k < 128) ? a.wih[n * 128 + k] : a.whh[n * 128 + (k - 128)];
    f16 h = (f16)x;
    a.hi[idx] = h;
    a.lo[idx] = (f16)(x - (float)h);
}

// ---------------------------------------------------------------------------
extern "C" void kernel_launch(void* const* d_in, const int* in_sizes, int n_in,
                              void* d_out, int out_size, void* d_ws, size_t ws_size,
                              hipStream_t stream) {
    const unsigned int* unpack = (const unsigned int*)d_in[1];

    Params p;
    p.vt      = (const int*)d_in[0];
    p.true_w  = (const float*)d_in[2];
    p.true_b  = (const float*)d_in[3];
    p.false_w = (const float*)d_in[4];
    p.false_b = (const float*)d_in[5];
    p.cm_b1 = (const float*)d_in[7];  p.cm_b2 = (const float*)d_in[9];
    p.cm_b3 = (const float*)d_in[11];
    p.pm_b1 = (const float*)d_in[13]; p.pm_b2 = (const float*)d_in[15];
    p.pm_b3 = (const float*)d_in[17];
    p.vv_b1 = (const float*)d_in[19]; p.vv_b2 = (const float*)d_in[21];
    p.vv_w3 = (const float*)d_in[22]; p.vv_b3 = (const float*)d_in[23];
    p.vu_bih = (const float*)d_in[26]; p.vu_bhh = (const float*)d_in[27];
    p.nu_bih = (const float*)d_in[30]; p.nu_bhh = (const float*)d_in[31];

    // workspace layout
    float* t1a = (float*)d_ws;                   // [12000][128]
    float* t1b = t1a + (size_t)NVARS * 128;      // [12000][128]
    int* ncnt = (int*)(t1b + (size_t)NVARS * 128);
    int* nidx = ncnt + NNODES;                   // [NNODES][CAP]
    int* vcnt = nidx + NNODES * CAP;
    int* vidx = vcnt + NVARS;                    // [NVARS][CAP]
    int* bar  = vidx + NVARS * CAP;              // 8 sharded counters, 64B apart
    uintptr_t wb = (uintptr_t)(bar + 128);
    wb = (wb + 15) & ~(uintptr_t)15;
    f16* wm_hi = (f16*)wb;            // 8*16384
    f16* wm_lo = wm_hi + 131072;
    f16* vu_hi = wm_lo + 131072;      // 512*256
    f16* vu_lo = vu_hi + 131072;
    f16* nu_hi = vu_lo + 131072;
    f16* nu_lo = nu_hi + 131072;

    p.t1a = t1a; p.t1b = t1b; p.bar = bar;
    p.ncnt = ncnt; p.nidx = nidx; p.vcnt = vcnt; p.vidx = vidx;
    p.wm_hi = wm_hi; p.wm_lo = wm_lo;
    p.vu_hi = vu_hi; p.vu_lo = vu_lo; p.nu_hi = nu_hi; p.nu_lo = nu_lo;
    p.out = (float*)d_out;

    (void)hipMemsetAsync(ncnt, 0, NNODES * sizeof(int), stream);
    (void)hipMemsetAsync(vcnt, 0, NVARS * sizeof(int), stream);
    (void)hipMemsetAsync(bar, 0, 128 * sizeof(int), stream);
    build_csr<<<4096, CTPB, 0, stream>>>(unpack, ncnt, nidx, vcnt, vidx);

    ConvMLP cm;
    cm.src[0] = (const float*)d_in[6];  cm.src[1] = (const float*)d_in[8];
    cm.src[2] = (const float*)d_in[10]; cm.src[3] = (const float*)d_in[12];
    cm.src[4] = (const float*)d_in[14]; cm.src[5] = (const float*)d_in[16];
    cm.src[6] = (const float*)d_in[18]; cm.src[7] = (const float*)d_in[20];
    cm.hi = wm_hi; cm.lo = wm_lo;
    conv_mlp<<<512, CTPB, 0, stream>>>(cm);

    ConvLSTM cv; cv.wih = (const float*)d_in[24]; cv.whh = (const float*)d_in[25];
    cv.hi = vu_hi; cv.lo = vu_lo;
    conv_lstm<<<512, CTPB, 0, stream>>>(cv);
    ConvLSTM cn; cn.wih = (const float*)d_in[28]; cn.whh = (const float*)d_in[29];
    cn.hi = nu_hi; cn.lo = nu_lo;
    conv_lstm<<<512, CTPB, 0, stream>>>(cn);

    mega<<<NB, TPB, 0, stream>>>(p);
}

// Round 10
// 1689.271 us; speedup vs baseline: 1.6542x; 1.0142x over previous
//
#include <hip/hip_runtime.h>

#define NVARS    12000
#define NNODES   8400
#define NLEAF    3600
#define NROUNDS  12
#define RPB      48              // rows per block (best weight amortization)
#define NB       250             // blocks (250*48 = 12000; node boundary = 175*48)
#define NODE_BLKS 175
#define CAP      64              // CSR fan-in cap (mean ~10, P(>64) ~ 0)
#define TPB      512             // 8 waves: wave w owns 16 output cols (B loaded once/block)
#define CTPB     256             // helper-kernel block size

typedef _Float16 f16;
typedef _Float16 half8 __attribute__((ext_vector_type(8)));
typedef _Float16 half4v __attribute__((ext_vector_type(4)));
typedef float f32x4 __attribute__((ext_vector_type(4)));
typedef unsigned long long ull;

#define MROW 136                 // LDS plane row stride in halves (272B, 16B-aligned)
#define PLANE (RPB * MROW)       // 6528 halves per plane

struct Params {
    float *t1a, *t1b;
    int *bar;
    const int *vt, *ncnt, *nidx, *vcnt, *vidx;
    const float *true_w, *true_b, *false_w, *false_b;
    const f16 *wm_hi, *wm_lo;          // 8 MLP mats [n=128][k=128] (lo unused)
    const f16 *vu_hi, *vu_lo;          // [512][256] (k<128: wih, k>=128: whh)
    const f16 *nu_hi, *nu_lo;
    const float *cm_b1, *cm_b2, *cm_b3, *pm_b1, *pm_b2, *pm_b3;
    const float *vv_b1, *vv_b2, *vv_w3, *vv_b3;
    const float *vu_bih, *vu_bhh, *nu_bih, *nu_bhh;
    float *out;
};

__device__ __forceinline__ float sigm(float x) { return 1.f / (1.f + expf(-x)); }

// ---- software grid barrier, FENCELESS (proven r3: -20%). Sharded arrivals,
// LOAD-only agent-scope spin; s_sleep(2) for tight release detection.
__device__ __forceinline__ void gsync(int* bar, int target) {
    __builtin_amdgcn_s_waitcnt(0);
    __syncthreads();
    if (threadIdx.x == 0) {
        __hip_atomic_fetch_add(&bar[(blockIdx.x & 7) << 4], 1,
                               __ATOMIC_RELAXED, __HIP_MEMORY_SCOPE_AGENT);
        for (;;) {
            int s = 0;
#pragma unroll
            for (int k = 0; k < 8; ++k)
                s += __hip_atomic_load(&bar[k << 4], __ATOMIC_RELAXED,
                                       __HIP_MEMORY_SCOPE_AGENT);
            if (s >= target) break;   // monotone counters: no false positive
            __builtin_amdgcn_s_sleep(2);
        }
    }
    __syncthreads();
}

// Precision scheme (r9+r10 probes): weights fp16 (accepted r9, absmax 2e-3);
// feed-forward activations (msg/a/b planes) fp16 (this round's probe);
// recurrent state h kept hi/lo split, c kept fp32, all accums fp32.

// ---- one 128->128 MLP layer, A input = hi/lo split planes (used for layer 1
// reading h). 8 waves: wave w owns output cols [w*16, w*16+16).
__device__ void layerM2(const f16* inHi, const f16* inLo,
                        const f16* Wh, const float* bias, bool relu,
                        f16* outP, float* gdst, int grow0) {
    const int lane = threadIdx.x & 63, l15 = lane & 15, quad = lane >> 4;
    const int w = threadIdx.x >> 6;          // 0..7
    half8 Bh[4];
#pragma unroll
    for (int s = 0; s < 4; ++s) {
        size_t off = (size_t)(w * 16 + l15) * 128 + s * 32 + quad * 8;
        Bh[s] = *(const half8*)(Wh + off);
    }
    const float b0 = bias[w * 16 + l15];
    const int col = w * 16 + l15;
#pragma unroll
    for (int mt = 0; mt < 3; ++mt) {
        half8 Ah[4], Al[4];
#pragma unroll
        for (int s = 0; s < 4; ++s) {
            int off = (mt * 16 + l15) * MROW + s * 32 + quad * 8;
            Ah[s] = *(const half8*)(inHi + off);
            Al[s] = *(const half8*)(inLo + off);
        }
        f32x4 acc = {0.f, 0.f, 0.f, 0.f};
#pragma unroll
        for (int s = 0; s < 4; ++s) {
            acc = __builtin_amdgcn_mfma_f32_16x16x32_f16(Ah[s], Bh[s], acc, 0, 0, 0);
            acc = __builtin_amdgcn_mfma_f32_16x16x32_f16(Al[s], Bh[s], acc, 0, 0, 0);
        }
#pragma unroll
        for (int reg = 0; reg < 4; ++reg) {
            int row = mt * 16 + quad * 4 + reg;
            float v = acc[reg] + b0;
            if (relu) v = fmaxf(v, 0.f);
            if (gdst) {
                __hip_atomic_store(&gdst[(size_t)(grow0 + row) * 128 + col], v,
                                   __ATOMIC_RELAXED, __HIP_MEMORY_SCOPE_AGENT);
            } else {
                outP[row * MROW + col] = (f16)v;
            }
        }
    }
    __syncthreads();
}

// ---- one 128->128 MLP layer, A input = single fp16 plane (layers 2/3, vote).
__device__ void layerM1(const f16* inP,
                        const f16* Wh, const float* bias, bool relu,
                        f16* outP, float* gdst, int grow0) {
    const int lane = threadIdx.x & 63, l15 = lane & 15, quad = lane >> 4;
    const int w = threadIdx.x >> 6;          // 0..7
    half8 Bh[4];
#pragma unroll
    for (int s = 0; s < 4; ++s) {
        size_t off = (size_t)(w * 16 + l15) * 128 + s * 32 + quad * 8;
        Bh[s] = *(const half8*)(Wh + off);
    }
    const float b0 = bias[w * 16 + l15];
    const int col = w * 16 + l15;
#pragma unroll
    for (int mt = 0; mt < 3; ++mt) {
        half8 Ah[4];
#pragma unroll
        for (int s = 0; s < 4; ++s) {
            int off = (mt * 16 + l15) * MROW + s * 32 + quad * 8;
            Ah[s] = *(const half8*)(inP + off);
        }
        f32x4 acc = {0.f, 0.f, 0.f, 0.f};
#pragma unroll
        for (int s = 0; s < 4; ++s)
            acc = __builtin_amdgcn_mfma_f32_16x16x32_f16(Ah[s], Bh[s], acc, 0, 0, 0);
#pragma unroll
        for (int reg = 0; reg < 4; ++reg) {
            int row = mt * 16 + quad * 4 + reg;
            float v = acc[reg] + b0;
            if (relu) v = fmaxf(v, 0.f);
            if (gdst) {
                __hip_atomic_store(&gdst[(size_t)(grow0 + row) * 128 + col], v,
                                   __ATOMIC_RELAXED, __HIP_MEMORY_SCOPE_AGENT);
            } else {
                outP[row * MROW + col] = (f16)v;
            }
        }
    }
    __syncthreads();
}

// ---- LSTM over the block's 48 rows: A=[msg(fp16); h(hi/lo)] (K=256),
// 512 gate cols. Wave w owns h-cols [w*16,w*16+16) of EACH gate ->
// pointwise in-register. Per (g,mt): 4 msg MFMA + 8 h MFMA (was 16).
__device__ void gatesL(const f16* msgP, f16* hHi, f16* hLo, float* cF,
                       const f16* Wh, const float* bih, const float* bhh) {
    const int lane = threadIdx.x & 63, l15 = lane & 15, quad = lane >> 4;
    const int w = threadIdx.x >> 6;          // 0..7
    float gb[4];
#pragma unroll
    for (int g = 0; g < 4; ++g)
        gb[g] = bih[g * 128 + w * 16 + l15] + bhh[g * 128 + w * 16 + l15];
    f32x4 acc[3][4];
#pragma unroll
    for (int mt = 0; mt < 3; ++mt)
#pragma unroll
        for (int g = 0; g < 4; ++g)
            acc[mt][g] = (f32x4){0.f, 0.f, 0.f, 0.f};

    for (int g = 0; g < 4; ++g) {
        half8 Bh[8];
#pragma unroll
        for (int s = 0; s < 8; ++s) {
            size_t off = (size_t)(g * 128 + w * 16 + l15) * 256 + s * 32 + quad * 8;
            Bh[s] = *(const half8*)(Wh + off);
        }
#pragma unroll
        for (int mt = 0; mt < 3; ++mt) {
            half8 Am[4], Ah[4], Al[4];
#pragma unroll
            for (int s = 0; s < 4; ++s) {
                int off = (mt * 16 + l15) * MROW + s * 32 + quad * 8;
                Am[s] = *(const half8*)(msgP + off);
                Ah[s] = *(const half8*)(hHi + off);
                Al[s] = *(const half8*)(hLo + off);
            }
#pragma unroll
            for (int s = 0; s < 4; ++s)       // K 0..127: msg (fp16)
                acc[mt][g] = __builtin_amdgcn_mfma_f32_16x16x32_f16(Am[s], Bh[s], acc[mt][g], 0, 0, 0);
#pragma unroll
            for (int s = 0; s < 4; ++s) {     // K 128..255: h (hi/lo)
                acc[mt][g] = __builtin_amdgcn_mfma_f32_16x16x32_f16(Ah[s], Bh[s + 4], acc[mt][g], 0, 0, 0);
                acc[mt][g] = __builtin_amdgcn_mfma_f32_16x16x32_f16(Al[s], Bh[s + 4], acc[mt][g], 0, 0, 0);
            }
        }
    }
    __syncthreads();   // all waves' A-reads of h done before pointwise rewrites h
    const int col = w * 16 + l15;
#pragma unroll
    for (int mt = 0; mt < 3; ++mt) {
#pragma unroll
        for (int reg = 0; reg < 4; ++reg) {
            int row = mt * 16 + quad * 4 + reg;
            float gi = acc[mt][0][reg] + gb[0];
            float gf = acc[mt][1][reg] + gb[1];
            float gg = acc[mt][2][reg] + gb[2];
            float go = acc[mt][3][reg] + gb[3];
            float cv = cF[row * 128 + col];
            float cn = sigm(gf) * cv + sigm(gi) * tanhf(gg);
            float hn = sigm(go) * tanhf(cn);
            cF[row * 128 + col] = cn;
            f16 hh = (f16)hn;
            hHi[row * MROW + col] = hh;
            hLo[row * MROW + col] = (f16)(hn - (float)hh);
        }
    }
    __syncthreads();
}

// ---- gather helpers: agent-scope 8B loads (bypass non-coherent L2)
__device__ __forceinline__ void ld8(ull* B, const float* t1g, int idx, int q) {
    const ull* s8 = (const ull*)(t1g + (size_t)idx * 128) + q * 8;
#pragma unroll
    for (int u = 0; u < 8; ++u)
        B[u] = __hip_atomic_load(s8 + u, __ATOMIC_RELAXED, __HIP_MEMORY_SCOPE_AGENT);
}
__device__ __forceinline__ void acc8(float* a, const ull* B) {
#pragma unroll
    for (int u = 0; u < 8; ++u) {
        union { ull q; float f[2]; } cv; cv.q = B[u];
        a[u * 2 + 0] += cv.f[0];
        a[u * 2 + 1] += cv.f[1];
    }
}

// ---- gather own 48 rows from global t1 into the msg plane (fp16).
// 8 threads/row x 48 rows = 384 of 512 threads. 4-deep ping-pong pipeline,
// j-order fp32 accumulation, single fp16 store at the end.
__device__ void gatherP(const float* t1g, const int* cnt, const int* idxm,
                        f16* msgP, int R0) {
    if (threadIdx.x < 8 * RPB) {
        int r = threadIdx.x >> 3, q = threadIdx.x & 7;
        int row = R0 + r;
        int n = cnt[row]; if (n > CAP) n = CAP;
        const int* ir = idxm + (size_t)row * CAP;
        float a[16];
#pragma unroll
        for (int u = 0; u < 16; ++u) a[u] = 0.f;
        ull b0[8], b1[8], b2[8], b3[8];
        if (n > 0) ld8(b0, t1g, ir[0], q);
        if (n > 1) ld8(b1, t1g, ir[1], q);
        if (n > 2) ld8(b2, t1g, ir[2], q);
        if (n > 3) ld8(b3, t1g, ir[3], q);
        for (int j = 0; j < n; j += 4) {
            acc8(a, b0);
            if (j + 4 < n) ld8(b0, t1g, ir[j + 4], q);
            if (j + 1 < n) {
                acc8(a, b1);
                if (j + 5 < n) ld8(b1, t1g, ir[j + 5], q);
            }
            if (j + 2 < n) {
                acc8(a, b2);
                if (j + 6 < n) ld8(b2, t1g, ir[j + 6], q);
            }
            if (j + 3 < n) {
                acc8(a, b3);
                if (j + 7 < n) ld8(b3, t1g, ir[j + 7], q);
            }
        }
#pragma unroll
        for (int u4 = 0; u4 < 4; ++u4) {
            half4v hh;
#pragma unroll
            for (int k = 0; k < 4; ++k)
                hh[k] = (f16)a[u4 * 4 + k];
            int off = r * MROW + q * 16 + u4 * 4;
            *(half4v*)(msgP + off) = hh;
        }
    }
    __syncthreads();
}

// ---------------------------------------------------------------------------
// launch_bounds(512,1): 1 block/CU, 8 waves (2/SIMD), 256-VGPR budget.
// NB=250 <= 256 CUs -> co-resident, grid barrier safe. LDS 77KB.
__global__ void __launch_bounds__(TPB, 1) mega(Params p) {
    __shared__ __align__(16) f16 smh[4 * PLANE];       // 52224 B (h hi/lo, a, b)
    __shared__ __align__(16) float cF[RPB * 128];      // 24576 B
    f16 *hHi = smh,             *hLo = smh + PLANE;
    f16 *aP  = smh + 2 * PLANE, *bP  = smh + 3 * PLANE;

    const int R0 = blockIdx.x * RPB;
    const bool isNode = blockIdx.x < NODE_BLKS;

    // init own rows: h0 = vt ? (tw+tb) : (fw+fb); c0 = 0
#pragma unroll
    for (int i = 0; i < (RPB * 128) / TPB; ++i) {
        int e = threadIdx.x + i * TPB;          // 0..6143
        int r = e >> 7, d = e & 127;
        float hv = (p.vt[R0 + r] == 1) ? (p.true_w[d] + p.true_b[d])
                                       : (p.false_w[d] + p.false_b[d]);
        f16 hh = (f16)hv;
        hHi[r * MROW + d] = hh;
        hLo[r * MROW + d] = (f16)(hv - (float)hh);
        cF[r * 128 + d] = 0.f;
    }
    __syncthreads();

    int ep = 0;
    for (int rd = 0; rd < NROUNDS; ++rd) {
        // cm MLP on own rows -> t1a
        layerM2(hHi, hLo, p.wm_hi + 0 * 16384, p.cm_b1, true,  aP, nullptr, 0);
        layerM1(aP,       p.wm_hi + 1 * 16384, p.cm_b2, true,  bP, nullptr, 0);
        layerM1(bP,       p.wm_hi + 2 * 16384, p.cm_b3, false, nullptr, p.t1a, R0);
        gsync(p.bar, ++ep * NB);
        if (isNode) {
            gatherP(p.t1a, p.ncnt, p.nidx, aP, R0);
            gatesL(aP, hHi, hLo, cF, p.vu_hi, p.vu_bih, p.vu_bhh);
            // pm MLP on own (node) rows -> t1b
            layerM2(hHi, hLo, p.wm_hi + 3 * 16384, p.pm_b1, true,  aP, nullptr, 0);
            layerM1(aP,       p.wm_hi + 4 * 16384, p.pm_b2, true,  bP, nullptr, 0);
            layerM1(bP,       p.wm_hi + 5 * 16384, p.pm_b3, false, nullptr, p.t1b, R0);
        }
        gsync(p.bar, ++ep * NB);
        gatherP(p.t1b, p.vcnt, p.vidx, aP, R0);
        gatesL(aP, hHi, hLo, cF, p.nu_hi, p.nu_bih, p.nu_bhh);
    }

    // vote on leaf blocks (4 threads/row, 32 cols each: same reduction order)
    if (!isNode) {
        layerM2(hHi, hLo, p.wm_hi + 6 * 16384, p.vv_b1, true, aP, nullptr, 0);
        layerM1(aP,       p.wm_hi + 7 * 16384, p.vv_b2, true, bP, nullptr, 0);
        if (threadIdx.x < 4 * RPB) {
            int r = threadIdx.x >> 2, q = threadIdx.x & 3;
            float s = 0.f;
#pragma unroll
            for (int u = 0; u < 32; ++u) {
                int col = q * 32 + u;
                s += (float)bP[r * MROW + col] * p.vv_w3[col];
            }
            s += __shfl_xor(s, 1);
            s += __shfl_xor(s, 2);
            if (q == 0) p.out[R0 - NNODES + r] = s + p.vv_b3[0];
        }
    }
}

// ---------------------------------------------------------------------------
__global__ void build_csr(const unsigned int* __restrict__ up,   // fp32 bits
                          int* __restrict__ ncnt, int* __restrict__ nidx,
                          int* __restrict__ vcnt, int* __restrict__ vidx) {
    const int total4 = NNODES * (NVARS / 4);
    const uint4* up4 = (const uint4*)up;
    for (int pidx = blockIdx.x * blockDim.x + threadIdx.x;
         pidx < total4; pidx += gridDim.x * blockDim.x) {
        uint4 w = up4[pidx];
        if ((w.x | w.y | w.z | w.w) == 0u) continue;
        int n  = pidx / (NVARS / 4);
        int v0 = (pidx % (NVARS / 4)) * 4;
        unsigned e[4] = { w.x, w.y, w.z, w.w };
#pragma unroll
        for (int j = 0; j < 4; ++j) {
            if (e[j]) {
                int v = v0 + j;
                int s1 = atomicAdd(&ncnt[n], 1);
                if (s1 < CAP) nidx[n * CAP + s1] = v;
                int s2 = atomicAdd(&vcnt[v], 1);
                if (s2 < CAP) vidx[v * CAP + s2] = n;
            }
        }
    }
}

struct ConvMLP { const float* src[8]; f16 *hi, *lo; };
__global__ void conv_mlp(ConvMLP a) {
    int idx = blockIdx.x * CTPB + threadIdx.x;
    if (idx >= 8 * 16384) return;
    float x = a.src[idx >> 14][idx & 16383];
    f16 h = (f16)x;
    a.hi[idx] = h;
    a.lo[idx] = (f16)(x - (float)h);
}

struct ConvLSTM { const float *wih, *whh; f16 *hi, *lo; };
__global__ void conv_lstm(ConvLSTM a) {
    int idx = blockIdx.x * CTPB + threadIdx.x;
    if (idx >= 512 * 256) return;
    int n = idx >> 8, k = idx & 255;
    float x = (k < 128) ? a.wih[n * 128 + k] : a.whh[n * 128 + (k - 128)];
    f16 h = (f16)x;
    a.hi[idx] = h;
    a.lo[idx] = (f16)(x - (float)h);
}

// ---------------------------------------------------------------------------
extern "C" void kernel_launch(void* const* d_in, const int* in_sizes, int n_in,
                              void* d_out, int out_size, void* d_ws, size_t ws_size,
                              hipStream_t stream) {
    const unsigned int* unpack = (const unsigned int*)d_in[1];

    Params p;
    p.vt      = (const int*)d_in[0];
    p.true_w  = (const float*)d_in[2];
    p.true_b  = (const float*)d_in[3];
    p.false_w = (const float*)d_in[4];
    p.false_b = (const float*)d_in[5];
    p.cm_b1 = (const float*)d_in[7];  p.cm_b2 = (const float*)d_in[9];
    p.cm_b3 = (const float*)d_in[11];
    p.pm_b1 = (const float*)d_in[13]; p.pm_b2 = (const float*)d_in[15];
    p.pm_b3 = (const float*)d_in[17];
    p.vv_b1 = (const float*)d_in[19]; p.vv_b2 = (const float*)d_in[21];
    p.vv_w3 = (const float*)d_in[22]; p.vv_b3 = (const float*)d_in[23];
    p.vu_bih = (const float*)d_in[26]; p.vu_bhh = (const float*)d_in[27];
    p.nu_bih = (const float*)d_in[30]; p.nu_bhh = (const float*)d_in[31];

    // workspace layout
    float* t1a = (float*)d_ws;                   // [12000][128]
    float* t1b = t1a + (size_t)NVARS * 128;      // [12000][128]
    int* ncnt = (int*)(t1b + (size_t)NVARS * 128);
    int* nidx = ncnt + NNODES;                   // [NNODES][CAP]
    int* vcnt = nidx + NNODES * CAP;
    int* vidx = vcnt + NVARS;                    // [NVARS][CAP]
    int* bar  = vidx + NVARS * CAP;              // 8 sharded counters, 64B apart
    uintptr_t wb = (uintptr_t)(bar + 128);
    wb = (wb + 15) & ~(uintptr_t)15;
    f16* wm_hi = (f16*)wb;            // 8*16384
    f16* wm_lo = wm_hi + 131072;
    f16* vu_hi = wm_lo + 131072;      // 512*256
    f16* vu_lo = vu_hi + 131072;
    f16* nu_hi = vu_lo + 131072;
    f16* nu_lo = nu_hi + 131072;

    p.t1a = t1a; p.t1b = t1b; p.bar = bar;
    p.ncnt = ncnt; p.nidx = nidx; p.vcnt = vcnt; p.vidx = vidx;
    p.wm_hi = wm_hi; p.wm_lo = wm_lo;
    p.vu_hi = vu_hi; p.vu_lo = vu_lo; p.nu_hi = nu_hi; p.nu_lo = nu_lo;
    p.out = (float*)d_out;

    (void)hipMemsetAsync(ncnt, 0, NNODES * sizeof(int), stream);
    (void)hipMemsetAsync(vcnt, 0, NVARS * sizeof(int), stream);
    (void)hipMemsetAsync(bar, 0, 128 * sizeof(int), stream);
    build_csr<<<4096, CTPB, 0, stream>>>(unpack, ncnt, nidx, vcnt, vidx);

    ConvMLP cm;
    cm.src[0] = (const float*)d_in[6];  cm.src[1] = (const float*)d_in[8];
    cm.src[2] = (const float*)d_in[10]; cm.src[3] = (const float*)d_in[12];
    cm.src[4] = (const float*)d_in[14]; cm.src[5] = (const float*)d_in[16];
    cm.src[6] = (const float*)d_in[18]; cm.src[7] = (const float*)d_in[20];
    cm.hi = wm_hi; cm.lo = wm_lo;
    conv_mlp<<<512, CTPB, 0, stream>>>(cm);

    ConvLSTM cv; cv.wih = (const float*)d_in[24]; cv.whh = (const float*)d_in[25];
    cv.hi = vu_hi; cv.lo = vu_lo;
    conv_lstm<<<512, CTPB, 0, stream>>>(cv);
    ConvLSTM cn; cn.wih = (const float*)d_in[28]; cn.whh = (const float*)d_in[29];
    cn.hi = nu_hi; cn.lo = nu_lo;
    conv_lstm<<<512, CTPB, 0, stream>>>(cn);

    mega<<<NB, TPB, 0, stream>>>(p);
}